// Round 1
// 87.172 us; speedup vs baseline: 1.0313x; 1.0313x over previous
//
#include <hip/hip_runtime.h>
#include <hip/hip_bf16.h>

// NT-Xent (SimCLR) fused loss, MI355X gfx950. Round 9: slim epilogue.
// - Row sums accumulated in registers (rs[16]) across ALL tiles of the
//   block (wave's rows don't depend on t); one shuffle+atomic flush at
//   block end instead of per tile (64 shfl + 16 atomics/tile -> 0).
// - Tile-kind specialization: diag mask only in (g==0,t==0), partner-pos
//   writes only in t==4 (jj=32) -- the only tiles where they can fire.
//   Common path: e = exp2f(acc * 10*log2e) = 1 mul + 1 v_exp + 2 adds.
// Structure (grid 8x64 persistent row-band blocks, fp8 MFMA, B-prefetch
// under epilogue) unchanged from Round 8.
//
// ws layout: [S: N floats][pos: N floats][zn8: N*D fp8 bytes]

#define N_TOT 8192
#define BATCH 4096
#define DIM   256                    // fp8 bytes per row
#define NT_TILES 64                  // 8192 / 128

typedef int   v8i32 __attribute__((ext_vector_type(8)));
typedef float f32x4 __attribute__((ext_vector_type(4)));

__device__ __forceinline__ void load_lds16(const void* g, void* l) {
  __builtin_amdgcn_global_load_lds(
      (const __attribute__((address_space(1))) unsigned int*)g,
      (__attribute__((address_space(3))) unsigned int*)l,
      16, 0, 0);
}

// One wave per row: 64 lanes x float4 -> 4 fp8 bytes/lane. Also zeros S.
__global__ __launch_bounds__(256) void normalize_kernel(
    const float* __restrict__ z, unsigned char* __restrict__ zn8,
    float* __restrict__ S) {
  const int wave = threadIdx.x >> 6;
  const int lane = threadIdx.x & 63;
  const int row  = blockIdx.x * 4 + wave;
  float4 v = ((const float4*)(z + (size_t)row * DIM))[lane];
  float ss = v.x * v.x + v.y * v.y + v.z * v.z + v.w * v.w;
#pragma unroll
  for (int m = 1; m <= 32; m <<= 1) ss += __shfl_xor(ss, m);
  float inv = 1.0f / sqrtf(ss);
  int p01 = __builtin_amdgcn_cvt_pk_fp8_f32(v.x * inv, v.y * inv, 0, false);
  int p23 = __builtin_amdgcn_cvt_pk_fp8_f32(v.z * inv, v.w * inv, 0, false);
  unsigned int packed =
      ((unsigned int)p01 & 0xffffu) | ((unsigned int)p23 << 16);
  ((unsigned int*)(zn8 + (size_t)row * DIM))[lane] = packed;
  if (threadIdx.x < 4) S[blockIdx.x * 4 + threadIdx.x] = 0.0f;
}

// Stage a 128-row band (full K = 256 B/row = 32 KB) into LDS.
// Per issue a wave writes 4 rows x 256 B = 1 KB; lane l -> row +(l>>4),
// LDS 16B-chunk (l&15); fetches global chunk (l&15)^(row&15) (XOR swizzle
// keeps fragment ds_read_b128 bank-balanced; measured 0 conflicts).
__device__ __forceinline__ void stage_band(
    const unsigned char* __restrict__ zn8, unsigned char* lds, int band,
    int wave, int lane) {
  const int srow = lane >> 4;          // 0..3
  const int slds = lane & 15;          // LDS chunk within row
  const size_t r0 = (size_t)band * 128;
#pragma unroll
  for (int t = 0; t < 8; ++t) {
    const int rloc = wave * 32 + t * 4 + srow;          // 0..127
    const int gch  = slds ^ (rloc & 15);                // swizzled source
    load_lds16(zn8 + (r0 + rloc) * DIM + gch * 16,
               lds + rloc * 256 + slds * 16);
  }
}

// Read one (row, k-half) fragment (32 bytes) from a swizzled band.
__device__ __forceinline__ v8i32 read_frag(const unsigned char* lds, int row,
                                           int h, int quad) {
  const int4* R = (const int4*)(lds + (size_t)row * 256);
  const int base = 8 * h + 2 * quad;   // even global chunk of this lane
  const int cc = row & 15;
  int4 lo = R[base ^ cc];
  int4 hi = R[(base + 1) ^ cc];
  return (v8i32){lo.x, lo.y, lo.z, lo.w, hi.x, hi.y, hi.z, hi.w};
}

// Tile epilogue. MODE 0 = plain, 1 = diagonal tile (mask self-sim, skip
// column flush), 2 = partner tile (jj==32: emit pos logits).
// Row sums accumulate into rs[16] (flushed once per block by caller);
// column sums reduce + atomic per tile (columns change every tile).
template <int MODE>
__device__ __forceinline__ void epilogue_tile(
    const f32x4 (&acc)[4][4], float (&rs)[16], float* __restrict__ S,
    float* __restrict__ pos, int rb, int cbt, int wm, int wn, int c,
    int quad) {
  float cs[4] = {0.f, 0.f, 0.f, 0.f};
#pragma unroll
  for (int fm = 0; fm < 4; ++fm) {
#pragma unroll
    for (int r = 0; r < 4; ++r) {
      const int grow = rb * 128 + wm * 64 + fm * 16 + quad * 4 + r;
#pragma unroll
      for (int fn = 0; fn < 4; ++fn) {
        const int gcol = cbt * 128 + wn * 64 + fn * 16 + c;
        // exp(acc*10) == exp2(acc * 10*log2(e))
        float e = exp2f(acc[fm][fn][r] * 14.4269504089f);
        if (MODE == 1 && gcol == grow) e = 0.f;   // exclude self-similarity
        if (MODE == 2 && ((gcol ^ grow) == BATCH)) {
          const float logit = acc[fm][fn][r] * 10.0f;
          pos[grow] = logit;                       // unique writer/elem
          pos[gcol] = logit;                       // sim symmetric
        }
        rs[fm * 4 + r] += e;
        cs[fn] += e;
      }
    }
  }
  if (MODE != 1) {
    // column sums -> S[col] (transpose contribution of this tile)
#pragma unroll
    for (int fn = 0; fn < 4; ++fn) {
      cs[fn] += __shfl_xor(cs[fn], 16);
      cs[fn] += __shfl_xor(cs[fn], 32);
    }
    if (quad == 0) {
#pragma unroll
      for (int fn = 0; fn < 4; ++fn)
        atomicAdd(&S[cbt * 128 + wn * 64 + fn * 16 + c], cs[fn]);
    }
  }
}

__global__ __launch_bounds__(256, 2) void simclr_tile_kernel(
    const unsigned char* __restrict__ zn8, float* __restrict__ S,
    float* __restrict__ pos) {
  const int g = blockIdx.x;                    // j-group 0..7
  const int rb = blockIdx.y;                   // row band 0..63 (A, fixed)
  const int tid = threadIdx.x;
  const int wave = tid >> 6, lane = tid & 63;
  const int wm = wave >> 1, wn = wave & 1;     // wave quadrant (2x2)
  const int c = lane & 15, quad = lane >> 4;   // MFMA lane coords

  __shared__ alignas(16) unsigned char As[128 * 256];   // 32 KB
  __shared__ alignas(16) unsigned char Bs[128 * 256];   // 32 KB

  const int ntile = (g == 0 && rb < 32) ? 5 : 4;  // g0 also does j=32

  stage_band(zn8, Bs, (rb + g * 4) & 63, wave, lane);   // B for tile 0
  stage_band(zn8, As, rb, wave, lane);                  // A, once per block
  __syncthreads();

  // A-fragments -> registers, reused across all tiles of this block.
  v8i32 af[4][2];
#pragma unroll
  for (int f = 0; f < 4; ++f)
#pragma unroll
    for (int h = 0; h < 2; ++h)
      af[f][h] = read_frag(As, wm * 64 + f * 16 + c, h, quad);

  // Per-row exp-sum partials, accumulated across ALL tiles of this block
  // (the wave's 16 output rows are the same for every tile).
  float rs[16];
#pragma unroll
  for (int i = 0; i < 16; ++i) rs[i] = 0.f;

  for (int t = 0; t < ntile; ++t) {
    const int jj = (t == 4) ? 32 : (g * 4 + t);
    const int cbt = (rb + jj) & 63;

    f32x4 acc[4][4];
#pragma unroll
    for (int i = 0; i < 4; ++i)
#pragma unroll
      for (int k = 0; k < 4; ++k) acc[i][k] = (f32x4){0.f, 0.f, 0.f, 0.f};

#pragma unroll
    for (int h = 0; h < 2; ++h) {
      v8i32 bfr[4];
#pragma unroll
      for (int f = 0; f < 4; ++f)
        bfr[f] = read_frag(Bs, wn * 64 + f * 16 + c, h, quad);
#pragma unroll
      for (int fm = 0; fm < 4; ++fm)
#pragma unroll
        for (int fn = 0; fn < 4; ++fn)
          acc[fm][fn] = __builtin_amdgcn_mfma_scale_f32_16x16x128_f8f6f4(
              af[fm][h], bfr[fn], acc[fm][fn],
              0, 0,                 // cbsz = fp8(A), blgp = fp8(B)
              0, 0x7f,              // opsel_a, scale_a = E8M0 1.0
              0, 0x7f);             // opsel_b, scale_b = E8M0 1.0
    }
    __syncthreads();                // all waves done reading Bs for tile t

    // Prefetch next B band NOW; its latency hides under the epilogue below.
    if (t + 1 < ntile) {
      const int jn = (t + 1 == 4) ? 32 : (g * 4 + t + 1);
      stage_band(zn8, Bs, (rb + jn) & 63, wave, lane);
    }

    // Epilogue, specialized per tile kind (uniform branch).
    if (g == 0 && t == 0)
      epilogue_tile<1>(acc, rs, S, pos, rb, cbt, wm, wn, c, quad);
    else if (t == 4)
      epilogue_tile<2>(acc, rs, S, pos, rb, cbt, wm, wn, c, quad);
    else
      epilogue_tile<0>(acc, rs, S, pos, rb, cbt, wm, wn, c, quad);

    if (t + 1 < ntile) __syncthreads();  // staging drained before next reads
  }

  // Flush per-row sums: one shuffle-reduce + atomic per row, once per block.
#pragma unroll
  for (int fm = 0; fm < 4; ++fm) {
#pragma unroll
    for (int r = 0; r < 4; ++r) {
      float s = rs[fm * 4 + r];
      s += __shfl_xor(s, 1);
      s += __shfl_xor(s, 2);
      s += __shfl_xor(s, 4);
      s += __shfl_xor(s, 8);
      if (c == 0) {
        const int grow = rb * 128 + wm * 64 + fm * 16 + quad * 4 + r;
        atomicAdd(&S[grow], s);
      }
    }
  }
}

// loss = mean(log(S_i) - pos_i)
__global__ __launch_bounds__(1024) void finalize_kernel(
    const float* __restrict__ S, const float* __restrict__ pos,
    float* __restrict__ out) {
  const int tid = threadIdx.x;
  float a = 0.f;
  for (int i = tid; i < N_TOT; i += 1024) a += __logf(S[i]) - pos[i];
#pragma unroll
  for (int m = 1; m <= 32; m <<= 1) a += __shfl_xor(a, m);
  __shared__ float red[16];
  if ((tid & 63) == 0) red[tid >> 6] = a;
  __syncthreads();
  if (tid < 16) {
    float v = red[tid];
    v += __shfl_xor(v, 1);
    v += __shfl_xor(v, 2);
    v += __shfl_xor(v, 4);
    v += __shfl_xor(v, 8);
    if (tid == 0) out[0] = v * (1.0f / (float)N_TOT);
  }
}

extern "C" void kernel_launch(void* const* d_in, const int* in_sizes, int n_in,
                              void* d_out, int out_size, void* d_ws,
                              size_t ws_size, hipStream_t stream) {
  const float* z = (const float*)d_in[0];
  float* out = (float*)d_out;
  char* ws = (char*)d_ws;
  float* S = (float*)ws;                                   // N floats
  float* pos = (float*)(ws + N_TOT * sizeof(float));       // N floats
  unsigned char* zn8 =
      (unsigned char*)(ws + 2 * N_TOT * sizeof(float));    // N*D fp8

  normalize_kernel<<<N_TOT / 4, 256, 0, stream>>>(z, zn8, S);
  dim3 grid(8, NT_TILES);
  simclr_tile_kernel<<<grid, 256, 0, stream>>>(zn8, S, pos);
  finalize_kernel<<<1, 1024, 0, stream>>>(S, pos, out);
}